// Round 1
// baseline (252.136 us; speedup 1.0000x reference)
//
#include <hip/hip_runtime.h>
#include <cstdint>

#define BATCH 4096
#define IN_DIM 1024
#define HID 2048
#define OUT_DIM 10
#define NTASKS 10

typedef __bf16 bf16x8 __attribute__((ext_vector_type(8)));
typedef float f32x4 __attribute__((ext_vector_type(4)));
typedef __attribute__((address_space(3))) uint8_t lds_u8;
typedef const __attribute__((address_space(1))) uint8_t glb_u8;

__device__ __forceinline__ unsigned short f2bf(float f) {
    uint32_t u = __builtin_bit_cast(uint32_t, f);
    u += 0x7fffu + ((u >> 16) & 1u);   // round-to-nearest-even
    return (unsigned short)(u >> 16);
}
__device__ __forceinline__ float bf2f(unsigned short h) {
    uint32_t u = ((uint32_t)h) << 16;
    return __builtin_bit_cast(float, u);
}

// ---------------- transform kernels ----------------

// w_bf16 = bf16(mu + exp(ls)*eps), vectorized x4
__global__ __launch_bounds__(256) void bl_transform(
    const float4* __restrict__ mu, const float4* __restrict__ ls,
    const float4* __restrict__ eps, ushort4* __restrict__ out, int n4)
{
    int i = blockIdx.x * blockDim.x + threadIdx.x;
    const int stride = gridDim.x * blockDim.x;
    for (; i < n4; i += stride) {
        const float4 m = mu[i], l = ls[i], e = eps[i];
        ushort4 r;
        r.x = f2bf(m.x + __expf(l.x) * e.x);
        r.y = f2bf(m.y + __expf(l.y) * e.y);
        r.z = f2bf(m.z + __expf(l.z) * e.z);
        r.w = f2bf(m.w + __expf(l.w) * e.w);
        out[i] = r;
    }
}

// fp32 -> bf16 conversion (for x)
__global__ __launch_bounds__(256) void bl_cvt(
    const float4* __restrict__ in, ushort4* __restrict__ out, int n4)
{
    int i = blockIdx.x * blockDim.x + threadIdx.x;
    const int stride = gridDim.x * blockDim.x;
    for (; i < n4; i += stride) {
        const float4 v = in[i];
        ushort4 r;
        r.x = f2bf(v.x); r.y = f2bf(v.y); r.z = f2bf(v.z); r.w = f2bf(v.w);
        out[i] = r;
    }
}

// small fp32 transforms: biases (b0, b1..3) and head weights/biases
__global__ __launch_bounds__(256) void bl_small(
    const float* __restrict__ mu_b0, const float* __restrict__ ls_b0, const float* __restrict__ eps_b0,
    const float* __restrict__ mu_b,  const float* __restrict__ ls_b,  const float* __restrict__ eps_b,
    const float* __restrict__ mu_hw, const float* __restrict__ ls_hw, const float* __restrict__ eps_hw,
    const float* __restrict__ mu_hb, const float* __restrict__ ls_hb, const float* __restrict__ eps_hb,
    float* __restrict__ b_all, float* __restrict__ hw, float* __restrict__ hb)
{
    const int total = HID + 3*HID + NTASKS*OUT_DIM*HID + NTASKS*OUT_DIM;
    int i = blockIdx.x * blockDim.x + threadIdx.x;
    const int stride = gridDim.x * blockDim.x;
    for (; i < total; i += stride) {
        if (i < HID) {
            b_all[i] = mu_b0[i] + __expf(ls_b0[i]) * eps_b0[i];
        } else if (i < 4*HID) {
            const int j = i - HID;
            b_all[HID + j] = mu_b[j] + __expf(ls_b[j]) * eps_b[j];
        } else if (i < 4*HID + NTASKS*OUT_DIM*HID) {
            const int j = i - 4*HID;
            hw[j] = mu_hw[j] + __expf(ls_hw[j]) * eps_hw[j];
        } else {
            const int j = i - (4*HID + NTASKS*OUT_DIM*HID);
            hb[j] = mu_hb[j] + __expf(ls_hb[j]) * eps_hb[j];
        }
    }
}

// ---------------- GEMM: C[M,N] = relu(A[M,K] @ B[N,K]^T + bias), bf16 in/out, fp32 acc
// m97 structure: 128x128 tile, BK=32, 4 waves each 64x64 (4x4 of 16x16x32 MFMA),
// global_load_lds width=16 staging, 2 barriers per K-step.
__global__ __launch_bounds__(256) void bl_gemm(
    const unsigned short* __restrict__ A,   // [4096][K] bf16
    const unsigned short* __restrict__ B,   // [2048][K] bf16
    const float* __restrict__ bias,         // [2048]
    unsigned short* __restrict__ C,         // [4096][2048] bf16
    int K)
{
    __shared__ unsigned short At[128 * 32];  // 8 KB
    __shared__ unsigned short Bt[128 * 32];  // 8 KB
    const int tid  = threadIdx.x;
    const int wave = tid >> 6;
    const int lane = tid & 63;
    const int bn = blockIdx.x;   // N tile (16)
    const int bm = blockIdx.y;   // M tile (32)
    const int wr = wave >> 1, wc = wave & 1;
    const int N = HID;

    // staging: lane l of chunk cidx loads 16B: row = cidx*16 + l/4, k-off = (l&3)*8
    const int srow = lane >> 2;
    const int skof = (lane & 3) * 8;
    const unsigned short* Ab = A + (size_t)(bm * 128 + srow) * K + skof;
    const unsigned short* Bb = B + (size_t)(bn * 128 + srow) * K + skof;

    // fragment read positions: row = l&15 (+16*m), k = (l>>4)*8
    const int rA = wr * 64 + (lane & 15);
    const int rB = wc * 64 + (lane & 15);
    const int kf = (lane >> 4) * 8;

    f32x4 acc[4][4] = {};

    for (int kt = 0; kt < K; kt += 32) {
        #pragma unroll
        for (int c = 0; c < 2; ++c) {
            const int cidx = wave * 2 + c;
            const unsigned short* ga = Ab + (size_t)(cidx * 16) * K + kt;
            const unsigned short* gb = Bb + (size_t)(cidx * 16) * K + kt;
            __builtin_amdgcn_global_load_lds((glb_u8*)ga, (lds_u8*)(((uint8_t*)At) + cidx * 1024), 16, 0, 0);
            __builtin_amdgcn_global_load_lds((glb_u8*)gb, (lds_u8*)(((uint8_t*)Bt) + cidx * 1024), 16, 0, 0);
        }
        __syncthreads();

        bf16x8 a[4], b[4];
        #pragma unroll
        for (int m = 0; m < 4; ++m)
            a[m] = *(const bf16x8*)(At + (rA + m * 16) * 32 + kf);
        #pragma unroll
        for (int n = 0; n < 4; ++n)
            b[n] = *(const bf16x8*)(Bt + (rB + n * 16) * 32 + kf);
        #pragma unroll
        for (int m = 0; m < 4; ++m)
            #pragma unroll
            for (int n = 0; n < 4; ++n)
                acc[m][n] = __builtin_amdgcn_mfma_f32_16x16x32_bf16(a[m], b[n], acc[m][n], 0, 0, 0);
        __syncthreads();
    }

    // epilogue: C/D layout col = lane&15, row = (lane>>4)*4 + j  [m89 verified]
    const int col0 = bn * 128 + wc * 64 + (lane & 15);
    const int row0 = bm * 128 + wr * 64 + ((lane >> 4) << 2);
    #pragma unroll
    for (int n = 0; n < 4; ++n) {
        const int col = col0 + n * 16;
        const float bv = bias[col];
        #pragma unroll
        for (int m = 0; m < 4; ++m) {
            #pragma unroll
            for (int j = 0; j < 4; ++j) {
                float v = acc[m][n][j] + bv;
                v = v > 0.0f ? v : 0.0f;
                C[(size_t)(row0 + m * 16 + j) * N + col] = f2bf(v);
            }
        }
    }
}

// ---------------- head: out[b,o] = sum_k h[b,k]*hw[task[b],o,k] + hb[task[b],o]
// one wave per batch row; fp32 head weights for accuracy
__global__ __launch_bounds__(256) void bl_head(
    const unsigned short* __restrict__ h,   // [4096][2048] bf16
    const float* __restrict__ hw,           // [10][10][2048] f32
    const float* __restrict__ hb,           // [10][10] f32
    const int* __restrict__ task,           // [4096] i32
    float* __restrict__ out)                // [4096][10] f32
{
    const int wave = threadIdx.x >> 6, lane = threadIdx.x & 63;
    const int b = blockIdx.x * 4 + wave;
    const int t = task[b];
    const float* w = hw + (size_t)t * OUT_DIM * HID;
    const unsigned short* hr = h + (size_t)b * HID;

    float acc[OUT_DIM];
    #pragma unroll
    for (int o = 0; o < OUT_DIM; ++o) acc[o] = 0.0f;

    for (int i = 0; i < HID / 64; ++i) {
        const int k = i * 64 + lane;
        const float hv = bf2f(hr[k]);
        #pragma unroll
        for (int o = 0; o < OUT_DIM; ++o)
            acc[o] += hv * w[(size_t)o * HID + k];
    }
    #pragma unroll
    for (int o = 0; o < OUT_DIM; ++o) {
        float v = acc[o];
        #pragma unroll
        for (int s = 32; s > 0; s >>= 1) v += __shfl_down(v, s, 64);
        if (lane == 0) out[(size_t)b * OUT_DIM + o] = v + hb[t * OUT_DIM + o];
    }
}

// ---------------- launch ----------------

extern "C" void kernel_launch(void* const* d_in, const int* in_sizes, int n_in,
                              void* d_out, int out_size, void* d_ws, size_t ws_size,
                              hipStream_t stream)
{
    const float* x      = (const float*)d_in[0];
    const float* mu_w0  = (const float*)d_in[1];
    const float* ls_w0  = (const float*)d_in[2];
    const float* mu_b0  = (const float*)d_in[3];
    const float* ls_b0  = (const float*)d_in[4];
    const float* mu_w   = (const float*)d_in[5];
    const float* ls_w   = (const float*)d_in[6];
    const float* mu_b   = (const float*)d_in[7];
    const float* ls_b   = (const float*)d_in[8];
    const float* mu_hw  = (const float*)d_in[9];
    const float* ls_hw  = (const float*)d_in[10];
    const float* mu_hb  = (const float*)d_in[11];
    const float* ls_hb  = (const float*)d_in[12];
    const float* eps_w0 = (const float*)d_in[13];
    const float* eps_b0 = (const float*)d_in[14];
    const float* eps_w  = (const float*)d_in[15];
    const float* eps_b  = (const float*)d_in[16];
    const float* eps_hw = (const float*)d_in[17];
    const float* eps_hb = (const float*)d_in[18];
    const int*   task   = (const int*)d_in[19];

    uint8_t* ws = (uint8_t*)d_ws;
    constexpr size_t X_OFF  = 0;
    constexpr size_t W0_OFF = X_OFF  + (size_t)BATCH * IN_DIM * 2;       // x bf16
    constexpr size_t W_OFF  = W0_OFF + (size_t)HID * IN_DIM * 2;         // w0 bf16
    constexpr size_t H0_OFF = W_OFF  + (size_t)3 * HID * HID * 2;        // w1..3 bf16
    constexpr size_t H1_OFF = H0_OFF + (size_t)BATCH * HID * 2;          // h ping
    constexpr size_t B_OFF  = H1_OFF + (size_t)BATCH * HID * 2;          // h pong
    constexpr size_t HW_OFF = B_OFF  + (size_t)4 * HID * 4;              // biases f32
    constexpr size_t HB_OFF = HW_OFF + (size_t)NTASKS * OUT_DIM * HID * 4;

    unsigned short* xbf = (unsigned short*)(ws + X_OFF);
    unsigned short* w0b = (unsigned short*)(ws + W0_OFF);
    unsigned short* wb  = (unsigned short*)(ws + W_OFF);
    unsigned short* h0  = (unsigned short*)(ws + H0_OFF);
    unsigned short* h1  = (unsigned short*)(ws + H1_OFF);
    float* ball = (float*)(ws + B_OFF);
    float* hwf  = (float*)(ws + HW_OFF);
    float* hbf  = (float*)(ws + HB_OFF);

    bl_cvt<<<1024, 256, 0, stream>>>((const float4*)x, (ushort4*)xbf, BATCH * IN_DIM / 4);
    bl_transform<<<1024, 256, 0, stream>>>((const float4*)mu_w0, (const float4*)ls_w0,
                                           (const float4*)eps_w0, (ushort4*)w0b, HID * IN_DIM / 4);
    bl_transform<<<2048, 256, 0, stream>>>((const float4*)mu_w, (const float4*)ls_w,
                                           (const float4*)eps_w, (ushort4*)wb, 3 * HID * HID / 4);
    bl_small<<<512, 256, 0, stream>>>(mu_b0, ls_b0, eps_b0, mu_b, ls_b, eps_b,
                                      mu_hw, ls_hw, eps_hw, mu_hb, ls_hb, eps_hb,
                                      ball, hwf, hbf);

    dim3 grid(HID / 128, BATCH / 128);   // (16, 32)
    bl_gemm<<<grid, 256, 0, stream>>>(xbf, w0b, ball,           h0, IN_DIM);
    bl_gemm<<<grid, 256, 0, stream>>>(h0, wb,                   ball + HID,     h1, HID);
    bl_gemm<<<grid, 256, 0, stream>>>(h1, wb + (size_t)HID*HID, ball + 2*HID,   h0, HID);
    bl_gemm<<<grid, 256, 0, stream>>>(h0, wb + (size_t)2*HID*HID, ball + 3*HID, h1, HID);

    bl_head<<<BATCH / 4, 256, 0, stream>>>(h1, hwf, hbf, task, (float*)d_out);
}

// Round 3
// 204.037 us; speedup vs baseline: 1.2357x; 1.2357x over previous
//
#include <hip/hip_runtime.h>
#include <cstdint>

#define BATCH 4096
#define IN_DIM 1024
#define HID 2048
#define OUT_DIM 10
#define NTASKS 10

typedef __bf16 bf16x8 __attribute__((ext_vector_type(8)));
typedef float f32x4 __attribute__((ext_vector_type(4)));
typedef __attribute__((address_space(3))) uint8_t lds_u8;
typedef const __attribute__((address_space(1))) uint8_t glb_u8;

__device__ __forceinline__ unsigned short f2bf(float f) {
    uint32_t u = __builtin_bit_cast(uint32_t, f);
    u += 0x7fffu + ((u >> 16) & 1u);   // round-to-nearest-even
    return (unsigned short)(u >> 16);
}
__device__ __forceinline__ float bf2f(unsigned short h) {
    uint32_t u = ((uint32_t)h) << 16;
    return __builtin_bit_cast(float, u);
}

// ---------------- transform kernels ----------------

__global__ __launch_bounds__(256) void bl_transform(
    const float4* __restrict__ mu, const float4* __restrict__ ls,
    const float4* __restrict__ eps, ushort4* __restrict__ out, int n4)
{
    int i = blockIdx.x * blockDim.x + threadIdx.x;
    const int stride = gridDim.x * blockDim.x;
    for (; i < n4; i += stride) {
        const float4 m = mu[i], l = ls[i], e = eps[i];
        ushort4 r;
        r.x = f2bf(m.x + __expf(l.x) * e.x);
        r.y = f2bf(m.y + __expf(l.y) * e.y);
        r.z = f2bf(m.z + __expf(l.z) * e.z);
        r.w = f2bf(m.w + __expf(l.w) * e.w);
        out[i] = r;
    }
}

__global__ __launch_bounds__(256) void bl_cvt(
    const float4* __restrict__ in, ushort4* __restrict__ out, int n4)
{
    int i = blockIdx.x * blockDim.x + threadIdx.x;
    const int stride = gridDim.x * blockDim.x;
    for (; i < n4; i += stride) {
        const float4 v = in[i];
        ushort4 r;
        r.x = f2bf(v.x); r.y = f2bf(v.y); r.z = f2bf(v.z); r.w = f2bf(v.w);
        out[i] = r;
    }
}

__global__ __launch_bounds__(256) void bl_small(
    const float* __restrict__ mu_b0, const float* __restrict__ ls_b0, const float* __restrict__ eps_b0,
    const float* __restrict__ mu_b,  const float* __restrict__ ls_b,  const float* __restrict__ eps_b,
    const float* __restrict__ mu_hw, const float* __restrict__ ls_hw, const float* __restrict__ eps_hw,
    const float* __restrict__ mu_hb, const float* __restrict__ ls_hb, const float* __restrict__ eps_hb,
    float* __restrict__ b_all, float* __restrict__ hw, float* __restrict__ hb)
{
    const int total = HID + 3*HID + NTASKS*OUT_DIM*HID + NTASKS*OUT_DIM;
    int i = blockIdx.x * blockDim.x + threadIdx.x;
    const int stride = gridDim.x * blockDim.x;
    for (; i < total; i += stride) {
        if (i < HID) {
            b_all[i] = mu_b0[i] + __expf(ls_b0[i]) * eps_b0[i];
        } else if (i < 4*HID) {
            const int j = i - HID;
            b_all[HID + j] = mu_b[j] + __expf(ls_b[j]) * eps_b[j];
        } else if (i < 4*HID + NTASKS*OUT_DIM*HID) {
            const int j = i - 4*HID;
            hw[j] = mu_hw[j] + __expf(ls_hw[j]) * eps_hw[j];
        } else {
            const int j = i - (4*HID + NTASKS*OUT_DIM*HID);
            hb[j] = mu_hb[j] + __expf(ls_hb[j]) * eps_hb[j];
        }
    }
}

// ---------------- GEMM: C[4096,2048] = relu(A[4096,K] @ B[2048,K]^T + bias)
// BM=256 BN=128 BK=64, 8 waves (4M x 2N, 64x64 each), double-buffered LDS (96KB),
// 4 phases per K-tile. Barriers are inline-asm s_barrier WITH "memory" clobber:
// the s_barrier BUILTIN is IntrNoMem in LLVM, so ds_read/global_load_lds could
// legally migrate across it at compile time -> the round-2 replay race.
// Full-drain points (prologue, end-of-tile buffer swap) use __syncthreads().
#define BAR()        asm volatile("s_barrier" ::: "memory")
#define WAIT_LGKM0() do { asm volatile("s_waitcnt lgkmcnt(0)" ::: "memory"); __builtin_amdgcn_sched_barrier(0); } while (0)
#define RD_A(m, o)   (*(const bf16x8*)(ldsb + acur + (o) + (m)*2048))
#define RD_B(n, o)   (*(const bf16x8*)(ldsb + bcur + (o) + (n)*2048))
#define MFMA(d, va, vb) d = __builtin_amdgcn_mfma_f32_16x16x32_bf16(va, vb, d, 0, 0, 0)
#define STAGEI(i, kel, sl) \
    __builtin_amdgcn_global_load_lds((glb_u8*)(gsrc[i] + (kel)), \
        (lds_u8*)(ldsb + ldst[i] + (uint32_t)(sl) * smul[i]), 16, 0, 0)

__global__ __launch_bounds__(512, 2) void bl_gemm(
    const unsigned short* __restrict__ A,   // [4096][K] bf16
    const unsigned short* __restrict__ B,   // [2048][K] bf16
    const float* __restrict__ bias,         // [2048]
    unsigned short* __restrict__ C,         // [4096][2048] bf16
    int K)
{
    // LDS: A slots @0 and @32768 bytes (256x64 bf16 each); B slots @65536, @81920 (128x64)
    __shared__ unsigned short lds[49152];   // 96 KB
    uint8_t* ldsb = (uint8_t*)lds;

    const int tid  = threadIdx.x;
    const int wave = tid >> 6;
    const int lane = tid & 63;
    // bijective XCD swizzle: nwg=256, 8 XCDs, 32 contiguous wgs per XCD
    const int swz = ((blockIdx.x & 7) << 5) | (blockIdx.x >> 3);
    const int bm = swz >> 4;        // 0..15  (M tiles of 256)
    const int bn = swz & 15;        // 0..15  (N tiles of 128)
    const int wr = wave >> 1;       // 0..3 -> m offset wr*64
    const int wc = wave & 1;        // 0..1 -> n offset wc*64

    // ---- staging setup: 48 chunks/tile (32 A + 16 B), 6 per wave ----
    // chunk c covers LDS linear bytes [c*1024, +1024) of its region = rows c*8..c*8+7.
    // lane l -> row = c*8 + (l>>3), 16B slot (l&7); swizzled source slot = (l&7)^(l>>3).
    const int lr8 = lane >> 3;
    const int ss  = (lane & 7) ^ lr8;
    const unsigned short* gsrc[6];
    uint32_t ldst[6], smul[6];
    #pragma unroll
    for (int i = 0; i < 6; ++i) {
        const int c = wave * 6 + i;
        if (c < 32) {
            gsrc[i] = A + (size_t)(bm * 256 + c * 8 + lr8) * K + ss * 8;
            ldst[i] = (uint32_t)c * 1024u;
            smul[i] = 32768u;
        } else {
            gsrc[i] = B + (size_t)(bn * 128 + (c - 32) * 8 + lr8) * K + ss * 8;
            ldst[i] = 65536u + (uint32_t)(c - 32) * 1024u;
            smul[i] = 16384u;
        }
    }

    // ---- fragment-read offsets (row stride 128B, slot ^= row&7 swizzle) ----
    const int rA = wr * 64 + (lane & 15);
    const int rB = wc * 64 + (lane & 15);
    const int ks = lane >> 4;                    // 16B slot within 32-wide k-block
    const uint32_t aoff0 = (uint32_t)(rA * 128 + ((ks       ^ (rA & 7)) * 16));
    const uint32_t aoff1 = (uint32_t)(rA * 128 + (((4 | ks) ^ (rA & 7)) * 16));
    const uint32_t boff0 = (uint32_t)(rB * 128 + ((ks       ^ (rB & 7)) * 16));
    const uint32_t boff1 = (uint32_t)(rB * 128 + (((4 | ks) ^ (rB & 7)) * 16));

    f32x4 acc[4][4] = {};
    const int NT = K >> 6;

    // ---- prologue: stage tile 0 into slot 0, full drain ----
    STAGEI(0, 0, 0); STAGEI(1, 0, 0); STAGEI(2, 0, 0);
    STAGEI(3, 0, 0); STAGEI(4, 0, 0); STAGEI(5, 0, 0);
    __syncthreads();

    for (int t = 0; t < NT; ++t) {
        const int cur = t & 1, nxt = cur ^ 1;
        const uint32_t acur = (uint32_t)cur * 32768u;
        const uint32_t bcur = 65536u + (uint32_t)cur * 16384u;
        const bool pf = (t + 1 < NT);
        const int ktn = (t + 1) << 6;

        bf16x8 a0, a1, a2, a3, b0, b1, b2, b3;

        // ---- phase 0: kk=0, m rows 0-1 ; issue first half of next-tile stage ----
        a0 = RD_A(0, aoff0); a1 = RD_A(1, aoff0);
        b0 = RD_B(0, boff0); b1 = RD_B(1, boff0); b2 = RD_B(2, boff0); b3 = RD_B(3, boff0);
        if (pf) { STAGEI(0, ktn, nxt); STAGEI(1, ktn, nxt); STAGEI(2, ktn, nxt); }
        BAR(); WAIT_LGKM0();
        __builtin_amdgcn_s_setprio(1);
        MFMA(acc[0][0], a0, b0); MFMA(acc[0][1], a0, b1); MFMA(acc[0][2], a0, b2); MFMA(acc[0][3], a0, b3);
        MFMA(acc[1][0], a1, b0); MFMA(acc[1][1], a1, b1); MFMA(acc[1][2], a1, b2); MFMA(acc[1][3], a1, b3);
        __builtin_amdgcn_s_setprio(0);
        BAR();

        // ---- phase 1: kk=0, m rows 2-3 ----
        a2 = RD_A(2, aoff0); a3 = RD_A(3, aoff0);
        BAR(); WAIT_LGKM0();
        __builtin_amdgcn_s_setprio(1);
        MFMA(acc[2][0], a2, b0); MFMA(acc[2][1], a2, b1); MFMA(acc[2][2], a2, b2); MFMA(acc[2][3], a2, b3);
        MFMA(acc[3][0], a3, b0); MFMA(acc[3][1], a3, b1); MFMA(acc[3][2], a3, b2); MFMA(acc[3][3], a3, b3);
        __builtin_amdgcn_s_setprio(0);
        BAR();

        // ---- phase 2: kk=1, m rows 0-1 ; issue second half of next-tile stage ----
        a0 = RD_A(0, aoff1); a1 = RD_A(1, aoff1);
        b0 = RD_B(0, boff1); b1 = RD_B(1, boff1); b2 = RD_B(2, boff1); b3 = RD_B(3, boff1);
        if (pf) { STAGEI(3, ktn, nxt); STAGEI(4, ktn, nxt); STAGEI(5, ktn, nxt); }
        BAR(); WAIT_LGKM0();
        __builtin_amdgcn_s_setprio(1);
        MFMA(acc[0][0], a0, b0); MFMA(acc[0][1], a0, b1); MFMA(acc[0][2], a0, b2); MFMA(acc[0][3], a0, b3);
        MFMA(acc[1][0], a1, b0); MFMA(acc[1][1], a1, b1); MFMA(acc[1][2], a1, b2); MFMA(acc[1][3], a1, b3);
        __builtin_amdgcn_s_setprio(0);
        BAR();

        // ---- phase 3: kk=1, m rows 2-3 ; full drain + barrier at buffer swap ----
        a2 = RD_A(2, aoff1); a3 = RD_A(3, aoff1);
        BAR(); WAIT_LGKM0();
        __builtin_amdgcn_s_setprio(1);
        MFMA(acc[2][0], a2, b0); MFMA(acc[2][1], a2, b1); MFMA(acc[2][2], a2, b2); MFMA(acc[2][3], a2, b3);
        MFMA(acc[3][0], a3, b0); MFMA(acc[3][1], a3, b1); MFMA(acc[3][2], a3, b2); MFMA(acc[3][3], a3, b3);
        __builtin_amdgcn_s_setprio(0);
        __syncthreads();   // waits vmcnt(0) lgkmcnt(0) + barrier, fully modeled
    }

    // ---- epilogue: bias + relu + bf16 store ----
    const int col0 = bn * 128 + wc * 64 + (lane & 15);
    const int row0 = bm * 256 + wr * 64 + ((lane >> 4) << 2);
    #pragma unroll
    for (int n = 0; n < 4; ++n) {
        const int col = col0 + n * 16;
        const float bv = bias[col];
        #pragma unroll
        for (int m = 0; m < 4; ++m) {
            #pragma unroll
            for (int j = 0; j < 4; ++j) {
                float v = acc[m][n][j] + bv;
                v = v > 0.0f ? v : 0.0f;
                C[(size_t)(row0 + m * 16 + j) * HID + col] = f2bf(v);
            }
        }
    }
}

// ---------------- head ----------------
__global__ __launch_bounds__(256) void bl_head(
    const unsigned short* __restrict__ h,   // [4096][2048] bf16
    const float* __restrict__ hw,           // [10][10][2048] f32
    const float* __restrict__ hb,           // [10][10] f32
    const int* __restrict__ task,           // [4096] i32
    float* __restrict__ out)                // [4096][10] f32
{
    const int wave = threadIdx.x >> 6, lane = threadIdx.x & 63;
    const int b = blockIdx.x * 4 + wave;
    const int t = task[b];
    const float* w = hw + (size_t)t * OUT_DIM * HID;
    const unsigned short* hr = h + (size_t)b * HID;

    float acc[OUT_DIM];
    #pragma unroll
    for (int o = 0; o < OUT_DIM; ++o) acc[o] = 0.0f;

    for (int i = 0; i < HID / 64; ++i) {
        const int k = i * 64 + lane;
        const float hv = bf2f(hr[k]);
        #pragma unroll
        for (int o = 0; o < OUT_DIM; ++o)
            acc[o] += hv * w[(size_t)o * HID + k];
    }
    #pragma unroll
    for (int o = 0; o < OUT_DIM; ++o) {
        float v = acc[o];
        #pragma unroll
        for (int s = 32; s > 0; s >>= 1) v += __shfl_down(v, s, 64);
        if (lane == 0) out[(size_t)b * OUT_DIM + o] = v + hb[t * OUT_DIM + o];
    }
}

// ---------------- launch ----------------

extern "C" void kernel_launch(void* const* d_in, const int* in_sizes, int n_in,
                              void* d_out, int out_size, void* d_ws, size_t ws_size,
                              hipStream_t stream)
{
    const float* x      = (const float*)d_in[0];
    const float* mu_w0  = (const float*)d_in[1];
    const float* ls_w0  = (const float*)d_in[2];
    const float* mu_b0  = (const float*)d_in[3];
    const float* ls_b0  = (const float*)d_in[4];
    const float* mu_w   = (const float*)d_in[5];
    const float* ls_w   = (const float*)d_in[6];
    const float* mu_b   = (const float*)d_in[7];
    const float* ls_b   = (const float*)d_in[8];
    const float* mu_hw  = (const float*)d_in[9];
    const float* ls_hw  = (const float*)d_in[10];
    const float* mu_hb  = (const float*)d_in[11];
    const float* ls_hb  = (const float*)d_in[12];
    const float* eps_w0 = (const float*)d_in[13];
    const float* eps_b0 = (const float*)d_in[14];
    const float* eps_w  = (const float*)d_in[15];
    const float* eps_b  = (const float*)d_in[16];
    const float* eps_hw = (const float*)d_in[17];
    const float* eps_hb = (const float*)d_in[18];
    const int*   task   = (const int*)d_in[19];

    uint8_t* ws = (uint8_t*)d_ws;
    constexpr size_t X_OFF  = 0;
    constexpr size_t W0_OFF = X_OFF  + (size_t)BATCH * IN_DIM * 2;       // x bf16
    constexpr size_t W_OFF  = W0_OFF + (size_t)HID * IN_DIM * 2;         // w0 bf16
    constexpr size_t H0_OFF = W_OFF  + (size_t)3 * HID * HID * 2;        // w1..3 bf16
    constexpr size_t H1_OFF = H0_OFF + (size_t)BATCH * HID * 2;          // h ping
    constexpr size_t B_OFF  = H1_OFF + (size_t)BATCH * HID * 2;          // h pong
    constexpr size_t HW_OFF = B_OFF  + (size_t)4 * HID * 4;              // biases f32
    constexpr size_t HB_OFF = HW_OFF + (size_t)NTASKS * OUT_DIM * HID * 4;

    unsigned short* xbf = (unsigned short*)(ws + X_OFF);
    unsigned short* w0b = (unsigned short*)(ws + W0_OFF);
    unsigned short* wb  = (unsigned short*)(ws + W_OFF);
    unsigned short* h0  = (unsigned short*)(ws + H0_OFF);
    unsigned short* h1  = (unsigned short*)(ws + H1_OFF);
    float* ball = (float*)(ws + B_OFF);
    float* hwf  = (float*)(ws + HW_OFF);
    float* hbf  = (float*)(ws + HB_OFF);

    bl_cvt<<<1024, 256, 0, stream>>>((const float4*)x, (ushort4*)xbf, BATCH * IN_DIM / 4);
    bl_transform<<<1024, 256, 0, stream>>>((const float4*)mu_w0, (const float4*)ls_w0,
                                           (const float4*)eps_w0, (ushort4*)w0b, HID * IN_DIM / 4);
    bl_transform<<<2048, 256, 0, stream>>>((const float4*)mu_w, (const float4*)ls_w,
                                           (const float4*)eps_w, (ushort4*)wb, 3 * HID * HID / 4);
    bl_small<<<512, 256, 0, stream>>>(mu_b0, ls_b0, eps_b0, mu_b, ls_b, eps_b,
                                      mu_hw, ls_hw, eps_hw, mu_hb, ls_hb, eps_hb,
                                      ball, hwf, hbf);

    bl_gemm<<<256, 512, 0, stream>>>(xbf, w0b, ball,             h0, IN_DIM);
    bl_gemm<<<256, 512, 0, stream>>>(h0, wb,                     ball + HID,   h1, HID);
    bl_gemm<<<256, 512, 0, stream>>>(h1, wb + (size_t)HID*HID,   ball + 2*HID, h0, HID);
    bl_gemm<<<256, 512, 0, stream>>>(h0, wb + (size_t)2*HID*HID, ball + 3*HID, h1, HID);

    bl_head<<<BATCH / 4, 256, 0, stream>>>(h1, hwf, hbf, task, (float*)d_out);
}